// Round 5
// baseline (1942.952 us; speedup 1.0000x reference)
//
#include <hip/hip_runtime.h>
#include <hip/hip_fp16.h>
#include <cmath>

#define NN 100000
#define NE 3200000
#define ET (NE + NN)       // edges + self loops
#define IN_CH 54
#define HID 32
#define OUTC 64
#define NG 512

__device__ __forceinline__ float lrelu(float v){ return fmaxf(v, 0.2f*v); }
__device__ __forceinline__ float mishf(float v){
    float sp = (v > 20.f) ? v : log1pf(__expf(v));
    return v * tanhf(sp);
}

// ---- CSR build ----
__global__ void k_count(const int* __restrict__ ei, int* __restrict__ deg){
    int e = blockIdx.x*blockDim.x + threadIdx.x;
    if (e >= ET) return;
    int dst = (e < NE) ? ei[NE + e] : (e - NE);
    atomicAdd(&deg[dst], 1);
}

__global__ void k_scan_a(const int* __restrict__ deg, int* __restrict__ bsum){
    int i = blockIdx.x*256 + threadIdx.x;
    int v = (i < NN) ? deg[i] : 0;
    __shared__ int ws[4];
    #pragma unroll
    for (int o = 1; o < 64; o <<= 1) v += __shfl_xor(v, o);
    if ((threadIdx.x & 63) == 0) ws[threadIdx.x >> 6] = v;
    __syncthreads();
    if (threadIdx.x == 0) bsum[blockIdx.x] = ws[0] + ws[1] + ws[2] + ws[3];
}

__global__ void k_scan_b(int* __restrict__ bsum, int nb){
    __shared__ int sh[512];
    int t = threadIdx.x;
    int orig = (t < nb) ? bsum[t] : 0;
    sh[t] = orig;
    __syncthreads();
    for (int o = 1; o < 512; o <<= 1){
        int v = (t >= o) ? sh[t-o] : 0;
        __syncthreads();
        sh[t] += v;
        __syncthreads();
    }
    if (t < nb) bsum[t] = sh[t] - orig;   // exclusive block offsets
}

__global__ void k_scan_c(const int* __restrict__ deg, const int* __restrict__ boff,
                         int* __restrict__ rp, int* __restrict__ cur){
    int b = blockIdx.x, t = threadIdx.x;
    int i = b*256 + t;
    int v = (i < NN) ? deg[i] : 0;
    __shared__ int sh[256];
    sh[t] = v;
    __syncthreads();
    for (int o = 1; o < 256; o <<= 1){
        int u = (t >= o) ? sh[t-o] : 0;
        __syncthreads();
        sh[t] += u;
        __syncthreads();
    }
    int excl = sh[t] - v + boff[b];
    if (i < NN){ rp[i] = excl; cur[i] = excl; }
    if (i == NN-1) rp[NN] = excl + v;
}

__global__ void k_fill(const int* __restrict__ ei, int* __restrict__ cur, int* __restrict__ col){
    int e = blockIdx.x*blockDim.x + threadIdx.x;
    if (e >= ET) return;
    int src = (e < NE) ? ei[e]      : (e - NE);
    int dst = (e < NE) ? ei[NE + e] : (e - NE);
    int p = atomicAdd(&cur[dst], 1);
    col[p] = src;
}

// ---- layer 1 linear: xl1 = x@Wl1+bl1, xr1 = x@Wr1+br1 (wave per node, fp16 out) ----
__global__ void k_gemm1(const float* __restrict__ x,
                        const float* __restrict__ Wl, const float* __restrict__ bl,
                        const float* __restrict__ Wr, const float* __restrict__ br,
                        __half* __restrict__ xl1, __half* __restrict__ xr1){
    int node = (blockIdx.x*blockDim.x + threadIdx.x) >> 6;
    int lane = threadIdx.x & 63;
    if (node >= NN) return;
    int c = lane & 31;
    const float* W = (lane < 32) ? Wl : Wr;
    float acc = (lane < 32) ? bl[c] : br[c];
    const float* xrow = x + (size_t)node * IN_CH;
    #pragma unroll 6
    for (int k = 0; k < IN_CH; ++k)
        acc += xrow[k] * W[k*HID + c];
    __half h = __float2half_rn(acc);
    if (lane < 32) xl1[node*HID + c] = h;
    else           xr1[node*HID + c] = h;
}

// ---- layer 1 edge aggregation: wave per dst node; 4 edge slots x 16 lanes x 2 ch ----
__global__ void k_edge1(const __half* __restrict__ xl1, const __half* __restrict__ xr1,
                        const float* __restrict__ att, const float* __restrict__ b1,
                        const int* __restrict__ rp, const int* __restrict__ col,
                        float* __restrict__ hout){
    int node = (blockIdx.x*blockDim.x + threadIdx.x) >> 6;
    int lane = threadIdx.x & 63;
    if (node >= NN) return;
    int cl = lane & 15;              // channel pair index: channels {2cl, 2cl+1}
    int slot = lane >> 4;            // 4 edge slots
    float2 xr = __half22float2(*(const __half2*)&xr1[node*HID + 2*cl]);
    float2 at = *(const float2*)&att[2*cl];
    float s = 0.f, acc0 = 0.f, acc1 = 0.f;
    int lo = rp[node], hi = rp[node+1];
    int deg = hi - lo;               // >= 1 (self loop)
    int cols = col[lo + min(lane, deg-1)];   // stage first 64 edge srcs
    int niter = (deg + 3) >> 2;
    int nit3 = ((niter + 2)/3)*3;

    auto eload = [&](int i)->unsigned{
        int idx  = slot + 4*i;
        int idxc = min(idx, deg-1);
        int src  = __shfl(cols, min(idxc, 63));
        if (idxc > 63) src = col[lo + idxc];   // rare fallback
        return *(const unsigned*)&xl1[src*HID + 2*cl];
    };
    auto eproc = [&](unsigned q, int i){
        bool valid = (slot + 4*i) < deg;
        float2 xlv = __half22float2(__builtin_bit_cast(__half2, q));
        float v0 = lrelu(xlv.x + xr.x), v1 = lrelu(xlv.y + xr.y);
        float p = v0*at.x + v1*at.y;
        p += __shfl_xor(p, 1);
        p += __shfl_xor(p, 2);       // 4-lane group = 8 channels = 1 head
        float w = valid ? __expf(p) : 0.f;
        s    += w;
        acc0 += w * xlv.x;
        acc1 += w * xlv.y;
    };

    unsigned q0 = eload(0);
    unsigned q1 = eload(1);
    unsigned q2 = eload(2);
    for (int i = 3; i < nit3; i += 3){
        eproc(q0, i-3); q0 = eload(i);
        eproc(q1, i-2); q1 = eload(i+1);
        eproc(q2, i-1); q2 = eload(i+2);
    }
    eproc(q0, nit3-3); eproc(q1, nit3-2); eproc(q2, nit3-1);

    // reduce across the 4 edge slots
    acc0 += __shfl_xor(acc0, 16); acc0 += __shfl_xor(acc0, 32);
    acc1 += __shfl_xor(acc1, 16); acc1 += __shfl_xor(acc1, 32);
    s    += __shfl_xor(s,    16); s    += __shfl_xor(s,    32);
    if (slot == 0){
        float inv = 1.f / (s + 1e-16f);
        float2 bb = *(const float2*)&b1[2*cl];
        float2 o;
        o.x = fmaxf(acc0*inv + bb.x, 0.f);
        o.y = fmaxf(acc1*inv + bb.y, 0.f);
        *(float2*)&hout[node*HID + 2*cl] = o;
    }
}

// ---- layer 2 linear (xl2 only): [N,32] @ [32,256] + bl2 -> fp16 ----
__global__ __launch_bounds__(256) void k_gemm2(const float* __restrict__ h,
                        const float* __restrict__ Wl, const float* __restrict__ bl,
                        __half* __restrict__ xl2){
    __shared__ float WS[HID*256];
    for (int i = threadIdx.x; i < HID*256; i += 256) WS[i] = Wl[i];
    __syncthreads();
    int lane = threadIdx.x & 63, wv = threadIdx.x >> 6;
    float4 b4 = *(const float4*)&bl[4*lane];
    int node0 = blockIdx.x * 32 + wv * 8;
    int nend = min(node0 + 8, NN);
    for (int n = node0; n < nend; ++n){
        const float* hr = h + n*HID;
        float4 a = {0.f,0.f,0.f,0.f};
        #pragma unroll 8
        for (int k = 0; k < HID; ++k){
            float hk = hr[k];
            float4 w = *(const float4*)&WS[k*256 + 4*lane];
            a.x += hk*w.x; a.y += hk*w.y; a.z += hk*w.z; a.w += hk*w.w;
        }
        ushort4 u;
        u.x = __half_as_ushort(__float2half_rn(a.x + b4.x));
        u.y = __half_as_ushort(__float2half_rn(a.y + b4.y));
        u.z = __half_as_ushort(__float2half_rn(a.z + b4.z));
        u.w = __half_as_ushort(__float2half_rn(a.w + b4.w));
        *(ushort4*)&xl2[(size_t)n*256 + 4*lane] = u;
    }
}

// ---- layer 2 edge aggregation + mish + pool ----
// v2 layout: wave = 1 dst node, 4 groups x 16 lanes; each group owns one edge per step.
// Lane l16=(h=l16&3, c=l16>>2) covers channels h*64+c*16 .. +15 (32B of fp16).
// Per 4 edges: 2 VMEM instrs, 2-hop logit reduce, 1 col-broadcast shfl.
__global__ __launch_bounds__(256) void k_edge2(const __half* __restrict__ xl2,
                        const float* __restrict__ h,
                        const float* __restrict__ Wr, const float* __restrict__ br,
                        const float* __restrict__ att, const float* __restrict__ b2,
                        const int* __restrict__ rp, const int* __restrict__ col,
                        const int* __restrict__ batch,
                        float* __restrict__ pool, float* __restrict__ cnt){
    int node = (blockIdx.x*blockDim.x + threadIdx.x) >> 6;
    int lane = threadIdx.x & 63;
    if (node >= NN) return;          // grid fits exactly; no partial blocks
    int wv   = (threadIdx.x >> 6);   // wave within block
    int l16  = lane & 15, g = lane >> 4;
    int hh   = l16 & 3, cc = l16 >> 2;
    int chb  = hh*64 + cc*16;        // my 16-channel base

    // --- xr2 row cooperatively in old layout (4 ch/lane), redistribute via LDS ---
    __shared__ float xrs[4][256];
    {
        int co = 4*lane;
        float4 xr4 = *(const float4*)&br[co];
        const float* hr = h + node*HID;
        #pragma unroll 8
        for (int k = 0; k < HID; ++k){
            float hk = hr[k];
            float4 w = *(const float4*)&Wr[k*256 + co];
            xr4.x += hk*w.x; xr4.y += hk*w.y; xr4.z += hk*w.z; xr4.w += hk*w.w;
        }
        *(float4*)&xrs[wv][co] = xr4;
    }
    __syncthreads();

    float xr[16], at[16];
    #pragma unroll
    for (int i = 0; i < 16; i += 4){
        *(float4*)&xr[i] = *(const float4*)&xrs[wv][chb + i];
        *(float4*)&at[i] = *(const float4*)&att[chb + i];
    }

    float acc[16];
    #pragma unroll
    for (int i = 0; i < 16; ++i) acc[i] = 0.f;
    float s = 0.f;

    int lo = rp[node], hi = rp[node+1];
    int deg  = hi - lo;              // >= 1
    int degc = min(deg, 64);
    int cols = col[lo + min(lane, deg-1)];   // stage first 64 edge srcs
    int nst  = (degc + 3) >> 2;              // steps of 4 edges
    int nst3 = ((nst + 2)/3)*3;              // padded; masked via valid

    uint4 A0,A1, B0,B1, C0,C1;

#define LOADQ(QA,QB, s_) do { \
        int eic_ = min(4*(s_) + g, degc-1); \
        int src_ = __shfl(cols, eic_); \
        const __half* rp_ = xl2 + (size_t)src_*256 + chb; \
        QA = *(const uint4*)rp_; \
        QB = *(const uint4*)(rp_ + 8); \
    } while(0)

#define PROC(QA,QB, s_) do { \
        bool valid_ = (4*(s_) + g) < degc; \
        float xlf[16]; float2 f_; \
        f_ = __half22float2(__builtin_bit_cast(__half2, QA.x)); xlf[0]=f_.x; xlf[1]=f_.y; \
        f_ = __half22float2(__builtin_bit_cast(__half2, QA.y)); xlf[2]=f_.x; xlf[3]=f_.y; \
        f_ = __half22float2(__builtin_bit_cast(__half2, QA.z)); xlf[4]=f_.x; xlf[5]=f_.y; \
        f_ = __half22float2(__builtin_bit_cast(__half2, QA.w)); xlf[6]=f_.x; xlf[7]=f_.y; \
        f_ = __half22float2(__builtin_bit_cast(__half2, QB.x)); xlf[8]=f_.x; xlf[9]=f_.y; \
        f_ = __half22float2(__builtin_bit_cast(__half2, QB.y)); xlf[10]=f_.x; xlf[11]=f_.y; \
        f_ = __half22float2(__builtin_bit_cast(__half2, QB.z)); xlf[12]=f_.x; xlf[13]=f_.y; \
        f_ = __half22float2(__builtin_bit_cast(__half2, QB.w)); xlf[14]=f_.x; xlf[15]=f_.y; \
        float p = 0.f; \
        _Pragma("unroll") \
        for (int i = 0; i < 16; ++i){ \
            float t_ = xlf[i] + xr[i]; \
            p += lrelu(t_) * at[i]; \
        } \
        p += __shfl_xor(p, 4); \
        p += __shfl_xor(p, 8); \
        float w_ = valid_ ? __expf(p) : 0.f; \
        s += w_; \
        _Pragma("unroll") \
        for (int i = 0; i < 16; ++i) acc[i] += w_ * xlf[i]; \
    } while(0)

    LOADQ(A0,A1, 0);
    LOADQ(B0,B1, 1);
    LOADQ(C0,C1, 2);
    for (int st = 3; st < nst3; st += 3){
        PROC(A0,A1, st-3); LOADQ(A0,A1, st);
        PROC(B0,B1, st-2); LOADQ(B0,B1, st+1);
        PROC(C0,C1, st-1); LOADQ(C0,C1, st+2);
    }
    PROC(A0,A1, nst3-3);
    PROC(B0,B1, nst3-2);
    PROC(C0,C1, nst3-1);

    // rare: edges beyond the first 64 (direct col loads, unpipelined)
    for (int eb = 64; eb < deg; eb += 4){
        int ei  = eb + g;
        int eic = min(ei, deg-1);
        int src = col[lo + eic];
        const __half* rp_ = xl2 + (size_t)src*256 + chb;
        uint4 qa = *(const uint4*)rp_;
        uint4 qb = *(const uint4*)(rp_ + 8);
        bool valid_ = ei < deg;
        float xlf[16]; float2 f_;
        f_ = __half22float2(__builtin_bit_cast(__half2, qa.x)); xlf[0]=f_.x; xlf[1]=f_.y;
        f_ = __half22float2(__builtin_bit_cast(__half2, qa.y)); xlf[2]=f_.x; xlf[3]=f_.y;
        f_ = __half22float2(__builtin_bit_cast(__half2, qa.z)); xlf[4]=f_.x; xlf[5]=f_.y;
        f_ = __half22float2(__builtin_bit_cast(__half2, qa.w)); xlf[6]=f_.x; xlf[7]=f_.y;
        f_ = __half22float2(__builtin_bit_cast(__half2, qb.x)); xlf[8]=f_.x; xlf[9]=f_.y;
        f_ = __half22float2(__builtin_bit_cast(__half2, qb.y)); xlf[10]=f_.x; xlf[11]=f_.y;
        f_ = __half22float2(__builtin_bit_cast(__half2, qb.z)); xlf[12]=f_.x; xlf[13]=f_.y;
        f_ = __half22float2(__builtin_bit_cast(__half2, qb.w)); xlf[14]=f_.x; xlf[15]=f_.y;
        float p = 0.f;
        #pragma unroll
        for (int i = 0; i < 16; ++i){ float t_ = xlf[i] + xr[i]; p += lrelu(t_) * at[i]; }
        p += __shfl_xor(p, 4);
        p += __shfl_xor(p, 8);
        float w_ = valid_ ? __expf(p) : 0.f;
        s += w_;
        #pragma unroll
        for (int i = 0; i < 16; ++i) acc[i] += w_ * xlf[i];
    }
#undef LOADQ
#undef PROC

    // --- epilogue ---
    // 1) total s per head (sum the 4 groups)
    s += __shfl_xor(s, 16); s += __shfl_xor(s, 32);
    float inv = 1.f / (s + 1e-16f);
    // 2) sum acc across groups, scale by per-head inv
    #pragma unroll
    for (int i = 0; i < 16; ++i){
        float a = acc[i];
        a += __shfl_xor(a, 16); a += __shfl_xor(a, 32);
        acc[i] = a * inv;
    }
    // 3) sum over heads (lanes differing in bits 0,1 share (c,i))
    #pragma unroll
    for (int i = 0; i < 16; ++i){
        float a = acc[i];
        a += __shfl_xor(a, 1); a += __shfl_xor(a, 2);
        acc[i] = a;
    }
    int grp = batch[node];
    if (g == 0 && hh == 0){          // lanes 0,4,8,12 -> 16 output channels each
        float* pg = pool + grp*OUTC;
        #pragma unroll
        for (int i = 0; i < 16; ++i){
            int j = cc*16 + i;
            float o = 0.25f*acc[i] + b2[j];
            atomicAdd(pg + j, mishf(o));
        }
    }
    if (lane == 0) atomicAdd(&cnt[grp], 1.0f);
}

__global__ void k_pool(const float* __restrict__ pool, const float* __restrict__ cnt,
                       float* __restrict__ out){
    int i = blockIdx.x*blockDim.x + threadIdx.x;
    if (i >= NG*OUTC) return;
    out[i] = pool[i] / fmaxf(cnt[i >> 6], 1.0f);
}

extern "C" void kernel_launch(void* const* d_in, const int* in_sizes, int n_in,
                              void* d_out, int out_size, void* d_ws, size_t ws_size,
                              hipStream_t stream){
    const float* x    = (const float*)d_in[0];
    const int*   ei   = (const int*)  d_in[1];
    const int*   batch= (const int*)  d_in[2];
    const float* Wl1  = (const float*)d_in[3];
    const float* bl1  = (const float*)d_in[4];
    const float* Wr1  = (const float*)d_in[5];
    const float* br1  = (const float*)d_in[6];
    const float* att1 = (const float*)d_in[7];
    const float* b1   = (const float*)d_in[8];
    const float* Wl2  = (const float*)d_in[9];
    const float* bl2  = (const float*)d_in[10];
    const float* Wr2  = (const float*)d_in[11];
    const float* br2  = (const float*)d_in[12];
    const float* att2 = (const float*)d_in[13];
    const float* b2   = (const float*)d_in[14];
    float* out = (float*)d_out;

    char* ws = (char*)d_ws;
    size_t off = 0;
    auto alloc = [&](size_t bytes)->char*{
        char* p = ws + off; off += (bytes + 255) & ~(size_t)255; return p;
    };
    __half* xl1  = (__half*)alloc((size_t)NN*HID*2);
    __half* xr1  = (__half*)alloc((size_t)NN*HID*2);
    float*  hbuf = (float*) alloc((size_t)NN*HID*4);
    __half* xl2  = (__half*)alloc((size_t)NN*256*2);
    int*    deg  = (int*)   alloc((size_t)NN*4);
    int*    rp   = (int*)   alloc((size_t)(NN+1)*4);
    int*    cur  = (int*)   alloc((size_t)NN*4);
    int*    col  = (int*)   alloc((size_t)ET*4);
    float*  pool = (float*) alloc((size_t)NG*OUTC*4);
    float*  cnt  = (float*) alloc((size_t)NG*4);
    int*    bsum = (int*)   alloc((size_t)512*4);

    const int NB = (NN + 255) / 256;   // 391

    hipMemsetAsync(deg,  0, (size_t)NN*4,      stream);
    hipMemsetAsync(pool, 0, (size_t)NG*OUTC*4, stream);
    hipMemsetAsync(cnt,  0, (size_t)NG*4,      stream);

    k_count <<<(ET+255)/256, 256, 0, stream>>>(ei, deg);
    k_scan_a<<<NB, 256, 0, stream>>>(deg, bsum);
    k_scan_b<<<1, 512, 0, stream>>>(bsum, NB);
    k_scan_c<<<NB, 256, 0, stream>>>(deg, bsum, rp, cur);
    k_fill  <<<(ET+255)/256, 256, 0, stream>>>(ei, cur, col);
    k_gemm1 <<<(NN+3)/4, 256, 0, stream>>>(x, Wl1, bl1, Wr1, br1, xl1, xr1);
    k_edge1 <<<(NN+3)/4, 256, 0, stream>>>(xl1, xr1, att1, b1, rp, col, hbuf);
    k_gemm2 <<<(NN+31)/32, 256, 0, stream>>>(hbuf, Wl2, bl2, xl2);
    k_edge2 <<<(NN+3)/4, 256, 0, stream>>>(xl2, hbuf, Wr2, br2, att2, b2, rp, col, batch, pool, cnt);
    k_pool  <<<(NG*OUTC+255)/256, 256, 0, stream>>>(pool, cnt, out);
}

// Round 7
// 1412.307 us; speedup vs baseline: 1.3757x; 1.3757x over previous
//
#include <hip/hip_runtime.h>
#include <hip/hip_fp16.h>
#include <cmath>

#define NN 100000
#define NE 3200000
#define ET (NE + NN)       // edges + self loops
#define IN_CH 54
#define HID 32
#define OUTC 64
#define NG 512

__device__ __forceinline__ float lrelu(float v){ return fmaxf(v, 0.2f*v); }
__device__ __forceinline__ float mishf(float v){
    float sp = (v > 20.f) ? v : log1pf(__expf(v));
    return v * tanhf(sp);
}

// ---- CSR build ----
__global__ void k_count(const int* __restrict__ ei, int* __restrict__ deg){
    int e = blockIdx.x*blockDim.x + threadIdx.x;
    if (e >= ET) return;
    int dst = (e < NE) ? ei[NE + e] : (e - NE);
    atomicAdd(&deg[dst], 1);
}

__global__ void k_scan_a(const int* __restrict__ deg, int* __restrict__ bsum){
    int i = blockIdx.x*256 + threadIdx.x;
    int v = (i < NN) ? deg[i] : 0;
    __shared__ int ws[4];
    #pragma unroll
    for (int o = 1; o < 64; o <<= 1) v += __shfl_xor(v, o);
    if ((threadIdx.x & 63) == 0) ws[threadIdx.x >> 6] = v;
    __syncthreads();
    if (threadIdx.x == 0) bsum[blockIdx.x] = ws[0] + ws[1] + ws[2] + ws[3];
}

__global__ void k_scan_b(int* __restrict__ bsum, int nb){
    __shared__ int sh[512];
    int t = threadIdx.x;
    int orig = (t < nb) ? bsum[t] : 0;
    sh[t] = orig;
    __syncthreads();
    for (int o = 1; o < 512; o <<= 1){
        int v = (t >= o) ? sh[t-o] : 0;
        __syncthreads();
        sh[t] += v;
        __syncthreads();
    }
    if (t < nb) bsum[t] = sh[t] - orig;   // exclusive block offsets
}

__global__ void k_scan_c(const int* __restrict__ deg, const int* __restrict__ boff,
                         int* __restrict__ rp, int* __restrict__ cur){
    int b = blockIdx.x, t = threadIdx.x;
    int i = b*256 + t;
    int v = (i < NN) ? deg[i] : 0;
    __shared__ int sh[256];
    sh[t] = v;
    __syncthreads();
    for (int o = 1; o < 256; o <<= 1){
        int u = (t >= o) ? sh[t-o] : 0;
        __syncthreads();
        sh[t] += u;
        __syncthreads();
    }
    int excl = sh[t] - v + boff[b];
    if (i < NN){ rp[i] = excl; cur[i] = excl; }
    if (i == NN-1) rp[NN] = excl + v;
}

__global__ void k_fill(const int* __restrict__ ei, int* __restrict__ cur, int* __restrict__ col){
    int e = blockIdx.x*blockDim.x + threadIdx.x;
    if (e >= ET) return;
    int src = (e < NE) ? ei[e]      : (e - NE);
    int dst = (e < NE) ? ei[NE + e] : (e - NE);
    int p = atomicAdd(&cur[dst], 1);
    col[p] = src;
}

// ---- layer 1 linear: xl1 = x@Wl1+bl1, xr1 = x@Wr1+br1 (wave per node, fp16 out) ----
__global__ void k_gemm1(const float* __restrict__ x,
                        const float* __restrict__ Wl, const float* __restrict__ bl,
                        const float* __restrict__ Wr, const float* __restrict__ br,
                        __half* __restrict__ xl1, __half* __restrict__ xr1){
    int node = (blockIdx.x*blockDim.x + threadIdx.x) >> 6;
    int lane = threadIdx.x & 63;
    if (node >= NN) return;
    int c = lane & 31;
    const float* W = (lane < 32) ? Wl : Wr;
    float acc = (lane < 32) ? bl[c] : br[c];
    const float* xrow = x + (size_t)node * IN_CH;
    #pragma unroll 6
    for (int k = 0; k < IN_CH; ++k)
        acc += xrow[k] * W[k*HID + c];
    __half h = __float2half_rn(acc);
    if (lane < 32) xl1[node*HID + c] = h;
    else           xr1[node*HID + c] = h;
}

// ---- layer 1 edge aggregation: wave per dst node; 4 edge slots x 16 lanes x 2 ch ----
// 2-deep software-pipelined gathers, uniform trip count (clamped idx + zero weight)
__global__ void k_edge1(const __half* __restrict__ xl1, const __half* __restrict__ xr1,
                        const float* __restrict__ att, const float* __restrict__ b1,
                        const int* __restrict__ rp, const int* __restrict__ col,
                        float* __restrict__ hout){
    int node = (blockIdx.x*blockDim.x + threadIdx.x) >> 6;
    int lane = threadIdx.x & 63;
    if (node >= NN) return;
    int cl = lane & 15;              // channel pair index: channels {2cl, 2cl+1}
    int slot = lane >> 4;            // 4 edge slots
    float2 xr = __half22float2(*(const __half2*)&xl1[0]);  // placeholder init (overwritten)
    xr = __half22float2(*(const __half2*)&xr1[node*HID + 2*cl]);
    float2 at = *(const float2*)&att[2*cl];
    float s = 0.f, acc0 = 0.f, acc1 = 0.f;
    int lo = rp[node], hi = rp[node+1];
    int deg = hi - lo;               // >= 1 (self loop)
    int niter = (deg + 3) >> 2;
    int e0 = lo + slot;

    auto eload = [&](int i)->unsigned{
        int e = e0 + 4*i;
        int ec = min(e, hi-1);
        return *(const unsigned*)&xl1[col[ec]*HID + 2*cl];
    };
    auto eproc = [&](unsigned q, bool valid){
        float2 xlv = __half22float2(__builtin_bit_cast(__half2, q));
        float t0 = xlv.x + xr.x, t1 = xlv.y + xr.y;
        float v0 = lrelu(t0), v1 = lrelu(t1);
        float p = v0*at.x + v1*at.y;
        p += __shfl_xor(p, 1);
        p += __shfl_xor(p, 2);       // 4-lane group = 8 channels = 1 head
        float w = valid ? __expf(p) : 0.f;
        s    += w;
        acc0 += w * xlv.x;
        acc1 += w * xlv.y;
    };

    unsigned q0 = eload(0); bool v0 = (e0 < hi);
    unsigned q1 = 0;        bool v1 = false;
    if (niter > 1){ q1 = eload(1); v1 = (e0 + 4 < hi); }
    for (int i = 2; i < niter; ++i){
        unsigned q2 = eload(i); bool v2 = (e0 + 4*i < hi);
        eproc(q0, v0);
        q0 = q1; v0 = v1; q1 = q2; v1 = v2;
    }
    eproc(q0, v0);
    if (niter > 1) eproc(q1, v1);

    // reduce across the 4 edge slots
    acc0 += __shfl_xor(acc0, 16); acc0 += __shfl_xor(acc0, 32);
    acc1 += __shfl_xor(acc1, 16); acc1 += __shfl_xor(acc1, 32);
    s    += __shfl_xor(s,    16); s    += __shfl_xor(s,    32);
    if (slot == 0){
        float inv = 1.f / (s + 1e-16f);
        float2 bb = *(const float2*)&b1[2*cl];
        float2 o;
        o.x = fmaxf(acc0*inv + bb.x, 0.f);
        o.y = fmaxf(acc1*inv + bb.y, 0.f);
        *(float2*)&hout[node*HID + 2*cl] = o;
    }
}

// ---- layer 2 linear (xl2 only): [N,32] @ [32,256] + bl2 -> fp16 ----
__global__ __launch_bounds__(256) void k_gemm2(const float* __restrict__ h,
                        const float* __restrict__ Wl, const float* __restrict__ bl,
                        __half* __restrict__ xl2){
    __shared__ float WS[HID*256];
    for (int i = threadIdx.x; i < HID*256; i += 256) WS[i] = Wl[i];
    __syncthreads();
    int lane = threadIdx.x & 63, wv = threadIdx.x >> 6;
    float4 b4 = *(const float4*)&bl[4*lane];
    int node0 = blockIdx.x * 32 + wv * 8;
    int nend = min(node0 + 8, NN);
    for (int n = node0; n < nend; ++n){
        const float* hr = h + n*HID;
        float4 a = {0.f,0.f,0.f,0.f};
        #pragma unroll 8
        for (int k = 0; k < HID; ++k){
            float hk = hr[k];
            float4 w = *(const float4*)&WS[k*256 + 4*lane];
            a.x += hk*w.x; a.y += hk*w.y; a.z += hk*w.z; a.w += hk*w.w;
        }
        ushort4 u;
        u.x = __half_as_ushort(__float2half_rn(a.x + b4.x));
        u.y = __half_as_ushort(__float2half_rn(a.y + b4.y));
        u.z = __half_as_ushort(__float2half_rn(a.z + b4.z));
        u.w = __half_as_ushort(__float2half_rn(a.w + b4.w));
        *(ushort4*)&xl2[(size_t)n*256 + 4*lane] = u;
    }
}

// ---- layer 2 edge aggregation + mish + pool ----
// v4: wave = 1 node; 2 edges per step (lane halves), 32 lanes x 16B per edge row.
// One dwordx4 per lane-half-pair = 1KB burst covering both edges' full fp16 rows.
// Head h (64 ch) = 8-lane group within a half; logit reduce = xor 1,2,4.
__global__ __launch_bounds__(256) void k_edge2(const __half* __restrict__ xl2,
                        const float* __restrict__ h,
                        const float* __restrict__ Wr, const float* __restrict__ br,
                        const float* __restrict__ att, const float* __restrict__ b2,
                        const int* __restrict__ rp, const int* __restrict__ col,
                        const int* __restrict__ batch,
                        float* __restrict__ pool, float* __restrict__ cnt){
    int node = (blockIdx.x*blockDim.x + threadIdx.x) >> 6;
    int lane = threadIdx.x & 63;
    if (node >= NN) return;
    int half = lane >> 5, l32 = lane & 31;
    int chb  = 8*l32;                 // my 8 consecutive fp16 channels (16B)

    // ---- xr2 for my 8 channels: full GEMV on every lane (halves redundant) ----
    float xr[8], at[8];
    {
        float4 bb0 = *(const float4*)&br[chb];
        float4 bb1 = *(const float4*)&br[chb + 4];
        xr[0]=bb0.x; xr[1]=bb0.y; xr[2]=bb0.z; xr[3]=bb0.w;
        xr[4]=bb1.x; xr[5]=bb1.y; xr[6]=bb1.z; xr[7]=bb1.w;
        const float* hr = h + node*HID;
        #pragma unroll 8
        for (int k = 0; k < HID; ++k){
            float hk = hr[k];
            const float* wrow = Wr + (size_t)k*256 + chb;
            float4 w0 = *(const float4*)wrow;
            float4 w1 = *(const float4*)(wrow + 4);
            xr[0] += hk*w0.x; xr[1] += hk*w0.y; xr[2] += hk*w0.z; xr[3] += hk*w0.w;
            xr[4] += hk*w1.x; xr[5] += hk*w1.y; xr[6] += hk*w1.z; xr[7] += hk*w1.w;
        }
        float4 t0 = *(const float4*)&att[chb];
        float4 t1 = *(const float4*)&att[chb + 4];
        at[0]=t0.x; at[1]=t0.y; at[2]=t0.z; at[3]=t0.w;
        at[4]=t1.x; at[5]=t1.y; at[6]=t1.z; at[7]=t1.w;
    }

    float s = 0.f;
    float acc[8];
    #pragma unroll
    for (int i = 0; i < 8; ++i) acc[i] = 0.f;

    int lo = rp[node], hi = rp[node+1];
    int deg = hi - lo;                // >= 1 (self loop)
    int ns   = (deg + 1) >> 1;        // steps of 2 edges
    int ns3  = ((ns + 2)/3)*3;        // padded to x3; masked via valid

    uint4 A, B, C;

#define GLD(Q, st_) do { \
        int ei_  = 2*(st_) + half; \
        int eic_ = min(ei_, deg-1); \
        int src_ = col[lo + eic_]; \
        Q = *(const uint4*)(xl2 + (size_t)src_*256 + chb); \
    } while(0)

#define PROC(Q, st_) do { \
        float2 f_; float xlf[8]; \
        f_ = __half22float2(__builtin_bit_cast(__half2, Q.x)); xlf[0]=f_.x; xlf[1]=f_.y; \
        f_ = __half22float2(__builtin_bit_cast(__half2, Q.y)); xlf[2]=f_.x; xlf[3]=f_.y; \
        f_ = __half22float2(__builtin_bit_cast(__half2, Q.z)); xlf[4]=f_.x; xlf[5]=f_.y; \
        f_ = __half22float2(__builtin_bit_cast(__half2, Q.w)); xlf[6]=f_.x; xlf[7]=f_.y; \
        float p_ = lrelu(xlf[0]+xr[0])*at[0] + lrelu(xlf[1]+xr[1])*at[1] \
                 + lrelu(xlf[2]+xr[2])*at[2] + lrelu(xlf[3]+xr[3])*at[3] \
                 + lrelu(xlf[4]+xr[4])*at[4] + lrelu(xlf[5]+xr[5])*at[5] \
                 + lrelu(xlf[6]+xr[6])*at[6] + lrelu(xlf[7]+xr[7])*at[7]; \
        p_ += __shfl_xor(p_, 1); \
        p_ += __shfl_xor(p_, 2); \
        p_ += __shfl_xor(p_, 4);      /* 8-lane group = 64 ch = 1 head */ \
        float w_ = ((2*(st_) + half) < deg) ? __expf(p_) : 0.f; \
        s += w_; \
        acc[0] += w_*xlf[0]; acc[1] += w_*xlf[1]; \
        acc[2] += w_*xlf[2]; acc[3] += w_*xlf[3]; \
        acc[4] += w_*xlf[4]; acc[5] += w_*xlf[5]; \
        acc[6] += w_*xlf[6]; acc[7] += w_*xlf[7]; \
    } while(0)

    GLD(A, 0);
    GLD(B, 1);
    GLD(C, 2);
    for (int st = 3; st < ns3; st += 3){
        PROC(A, st-3); GLD(A, st);
        PROC(B, st-2); GLD(B, st+1);
        PROC(C, st-1); GLD(C, st+2);
    }
    PROC(A, ns3-3);
    PROC(B, ns3-2);
    PROC(C, ns3-1);
#undef GLD
#undef PROC

    // ---- epilogue ----
    s += __shfl_xor(s, 32);           // combine halves (same head group)
    float inv = 1.f / (s + 1e-16f);
    #pragma unroll
    for (int i = 0; i < 8; ++i){
        float v = acc[i] + __shfl_xor(acc[i], 32);  // combine halves
        v *= inv;                     // per-head normalization
        v += __shfl_xor(v, 8);        // sum over 4 heads (bits 3,4 of l32)
        v += __shfl_xor(v, 16);
        acc[i] = v;
    }
    int grp = batch[node];
    if (half == 0 && l32 < 8){        // lanes 0..7 -> channels 8*l32 .. +7
        float* pg = pool + grp*OUTC + 8*l32;
        const float* bb = b2 + 8*l32;
        #pragma unroll
        for (int i = 0; i < 8; ++i)
            atomicAdd(pg + i, mishf(0.25f*acc[i] + bb[i]));
    }
    if (lane == 0) atomicAdd(&cnt[grp], 1.0f);
}

__global__ void k_pool(const float* __restrict__ pool, const float* __restrict__ cnt,
                       float* __restrict__ out){
    int i = blockIdx.x*blockDim.x + threadIdx.x;
    if (i >= NG*OUTC) return;
    out[i] = pool[i] / fmaxf(cnt[i >> 6], 1.0f);
}

extern "C" void kernel_launch(void* const* d_in, const int* in_sizes, int n_in,
                              void* d_out, int out_size, void* d_ws, size_t ws_size,
                              hipStream_t stream){
    const float* x    = (const float*)d_in[0];
    const int*   ei   = (const int*)  d_in[1];
    const int*   batch= (const int*)  d_in[2];
    const float* Wl1  = (const float*)d_in[3];
    const float* bl1  = (const float*)d_in[4];
    const float* Wr1  = (const float*)d_in[5];
    const float* br1  = (const float*)d_in[6];
    const float* att1 = (const float*)d_in[7];
    const float* b1   = (const float*)d_in[8];
    const float* Wl2  = (const float*)d_in[9];
    const float* bl2  = (const float*)d_in[10];
    const float* Wr2  = (const float*)d_in[11];
    const float* br2  = (const float*)d_in[12];
    const float* att2 = (const float*)d_in[13];
    const float* b2   = (const float*)d_in[14];
    float* out = (float*)d_out;

    char* ws = (char*)d_ws;
    size_t off = 0;
    auto alloc = [&](size_t bytes)->char*{
        char* p = ws + off; off += (bytes + 255) & ~(size_t)255; return p;
    };
    __half* xl1  = (__half*)alloc((size_t)NN*HID*2);
    __half* xr1  = (__half*)alloc((size_t)NN*HID*2);
    float*  hbuf = (float*) alloc((size_t)NN*HID*4);
    __half* xl2  = (__half*)alloc((size_t)NN*256*2);
    int*    deg  = (int*)   alloc((size_t)NN*4);
    int*    rp   = (int*)   alloc((size_t)(NN+1)*4);
    int*    cur  = (int*)   alloc((size_t)NN*4);
    int*    col  = (int*)   alloc((size_t)ET*4);
    float*  pool = (float*) alloc((size_t)NG*OUTC*4);
    float*  cnt  = (float*) alloc((size_t)NG*4);
    int*    bsum = (int*)   alloc((size_t)512*4);

    const int NB = (NN + 255) / 256;   // 391

    hipMemsetAsync(deg,  0, (size_t)NN*4,      stream);
    hipMemsetAsync(pool, 0, (size_t)NG*OUTC*4, stream);
    hipMemsetAsync(cnt,  0, (size_t)NG*4,      stream);

    k_count <<<(ET+255)/256, 256, 0, stream>>>(ei, deg);
    k_scan_a<<<NB, 256, 0, stream>>>(deg, bsum);
    k_scan_b<<<1, 512, 0, stream>>>(bsum, NB);
    k_scan_c<<<NB, 256, 0, stream>>>(deg, bsum, rp, cur);
    k_fill  <<<(ET+255)/256, 256, 0, stream>>>(ei, cur, col);
    k_gemm1 <<<(NN+3)/4, 256, 0, stream>>>(x, Wl1, bl1, Wr1, br1, xl1, xr1);
    k_edge1 <<<(NN+3)/4, 256, 0, stream>>>(xl1, xr1, att1, b1, rp, col, hbuf);
    k_gemm2 <<<(NN+31)/32, 256, 0, stream>>>(hbuf, Wl2, bl2, xl2);
    k_edge2 <<<(NN+3)/4, 256, 0, stream>>>(xl2, hbuf, Wr2, br2, att2, b2, rp, col, batch, pool, cnt);
    k_pool  <<<(NG*OUTC+255)/256, 256, 0, stream>>>(pool, cnt, out);
}

// Round 8
// 1296.674 us; speedup vs baseline: 1.4984x; 1.0892x over previous
//
#include <hip/hip_runtime.h>
#include <hip/hip_fp16.h>
#include <cmath>

#define NN 100000
#define NE 3200000
#define ET (NE + NN)       // edges + self loops
#define IN_CH 54
#define HID 32
#define OUTC 64
#define NG 512

__device__ __forceinline__ float lrelu(float v){ return fmaxf(v, 0.2f*v); }
__device__ __forceinline__ float mishf(float v){
    float sp = (v > 20.f) ? v : log1pf(__expf(v));
    return v * tanhf(sp);
}

// ---- CSR build ----
__global__ void k_count(const int* __restrict__ ei, int* __restrict__ deg){
    int e = blockIdx.x*blockDim.x + threadIdx.x;
    if (e >= ET) return;
    int dst = (e < NE) ? ei[NE + e] : (e - NE);
    atomicAdd(&deg[dst], 1);
}

__global__ void k_scan_a(const int* __restrict__ deg, int* __restrict__ bsum){
    int i = blockIdx.x*256 + threadIdx.x;
    int v = (i < NN) ? deg[i] : 0;
    __shared__ int ws[4];
    #pragma unroll
    for (int o = 1; o < 64; o <<= 1) v += __shfl_xor(v, o);
    if ((threadIdx.x & 63) == 0) ws[threadIdx.x >> 6] = v;
    __syncthreads();
    if (threadIdx.x == 0) bsum[blockIdx.x] = ws[0] + ws[1] + ws[2] + ws[3];
}

__global__ void k_scan_b(int* __restrict__ bsum, int nb){
    __shared__ int sh[512];
    int t = threadIdx.x;
    int orig = (t < nb) ? bsum[t] : 0;
    sh[t] = orig;
    __syncthreads();
    for (int o = 1; o < 512; o <<= 1){
        int v = (t >= o) ? sh[t-o] : 0;
        __syncthreads();
        sh[t] += v;
        __syncthreads();
    }
    if (t < nb) bsum[t] = sh[t] - orig;   // exclusive block offsets
}

__global__ void k_scan_c(const int* __restrict__ deg, const int* __restrict__ boff,
                         int* __restrict__ rp, int* __restrict__ cur){
    int b = blockIdx.x, t = threadIdx.x;
    int i = b*256 + t;
    int v = (i < NN) ? deg[i] : 0;
    __shared__ int sh[256];
    sh[t] = v;
    __syncthreads();
    for (int o = 1; o < 256; o <<= 1){
        int u = (t >= o) ? sh[t-o] : 0;
        __syncthreads();
        sh[t] += u;
        __syncthreads();
    }
    int excl = sh[t] - v + boff[b];
    if (i < NN){ rp[i] = excl; cur[i] = excl; }
    if (i == NN-1) rp[NN] = excl + v;
}

__global__ void k_fill(const int* __restrict__ ei, int* __restrict__ cur, int* __restrict__ col){
    int e = blockIdx.x*blockDim.x + threadIdx.x;
    if (e >= ET) return;
    int src = (e < NE) ? ei[e]      : (e - NE);
    int dst = (e < NE) ? ei[NE + e] : (e - NE);
    int p = atomicAdd(&cur[dst], 1);
    col[p] = src;
}

// ---- layer 1 linear: xl1 = x@Wl1+bl1, xr1 = x@Wr1+br1 (wave per node, fp16 out) ----
__global__ void k_gemm1(const float* __restrict__ x,
                        const float* __restrict__ Wl, const float* __restrict__ bl,
                        const float* __restrict__ Wr, const float* __restrict__ br,
                        __half* __restrict__ xl1, __half* __restrict__ xr1){
    int node = (blockIdx.x*blockDim.x + threadIdx.x) >> 6;
    int lane = threadIdx.x & 63;
    if (node >= NN) return;
    int c = lane & 31;
    const float* W = (lane < 32) ? Wl : Wr;
    float acc = (lane < 32) ? bl[c] : br[c];
    const float* xrow = x + (size_t)node * IN_CH;
    #pragma unroll 6
    for (int k = 0; k < IN_CH; ++k)
        acc += xrow[k] * W[k*HID + c];
    __half h = __float2half_rn(acc);
    if (lane < 32) xl1[node*HID + c] = h;
    else           xr1[node*HID + c] = h;
}

// ---- layer 1 edge aggregation: wave per dst node; 4 edge slots x 16 lanes x 2 ch ----
// 2-deep software-pipelined gathers (nontemporal: bypass L1), uniform trip count
__global__ void k_edge1(const __half* __restrict__ xl1, const __half* __restrict__ xr1,
                        const float* __restrict__ att, const float* __restrict__ b1,
                        const int* __restrict__ rp, const int* __restrict__ col,
                        float* __restrict__ hout){
    int node = (blockIdx.x*blockDim.x + threadIdx.x) >> 6;
    int lane = threadIdx.x & 63;
    if (node >= NN) return;
    int cl = lane & 15;              // channel pair index: channels {2cl, 2cl+1}
    int slot = lane >> 4;            // 4 edge slots
    float2 xr = __half22float2(*(const __half2*)&xr1[node*HID + 2*cl]);
    float2 at = *(const float2*)&att[2*cl];
    float s = 0.f, acc0 = 0.f, acc1 = 0.f;
    int lo = rp[node], hi = rp[node+1];
    int deg = hi - lo;               // >= 1 (self loop)
    int niter = (deg + 3) >> 2;
    int e0 = lo + slot;

    auto eload = [&](int i)->unsigned{
        int e = e0 + 4*i;
        int ec = min(e, hi-1);
        return __builtin_nontemporal_load(
            (const unsigned*)&xl1[col[ec]*HID + 2*cl]);
    };
    auto eproc = [&](unsigned q, bool valid){
        float2 xlv = __half22float2(__builtin_bit_cast(__half2, q));
        float t0 = xlv.x + xr.x, t1 = xlv.y + xr.y;
        float v0 = lrelu(t0), v1 = lrelu(t1);
        float p = v0*at.x + v1*at.y;
        p += __shfl_xor(p, 1);
        p += __shfl_xor(p, 2);       // 4-lane group = 8 channels = 1 head
        float w = valid ? __expf(p) : 0.f;
        s    += w;
        acc0 += w * xlv.x;
        acc1 += w * xlv.y;
    };

    unsigned q0 = eload(0); bool v0 = (e0 < hi);
    unsigned q1 = 0;        bool v1 = false;
    if (niter > 1){ q1 = eload(1); v1 = (e0 + 4 < hi); }
    for (int i = 2; i < niter; ++i){
        unsigned q2 = eload(i); bool v2 = (e0 + 4*i < hi);
        eproc(q0, v0);
        q0 = q1; v0 = v1; q1 = q2; v1 = v2;
    }
    eproc(q0, v0);
    if (niter > 1) eproc(q1, v1);

    // reduce across the 4 edge slots
    acc0 += __shfl_xor(acc0, 16); acc0 += __shfl_xor(acc0, 32);
    acc1 += __shfl_xor(acc1, 16); acc1 += __shfl_xor(acc1, 32);
    s    += __shfl_xor(s,    16); s    += __shfl_xor(s,    32);
    if (slot == 0){
        float inv = 1.f / (s + 1e-16f);
        float2 bb = *(const float2*)&b1[2*cl];
        float2 o;
        o.x = fmaxf(acc0*inv + bb.x, 0.f);
        o.y = fmaxf(acc1*inv + bb.y, 0.f);
        *(float2*)&hout[node*HID + 2*cl] = o;
    }
}

// ---- layer 2 linear (xl2 only): [N,32] @ [32,256] + bl2 -> fp16 ----
__global__ __launch_bounds__(256) void k_gemm2(const float* __restrict__ h,
                        const float* __restrict__ Wl, const float* __restrict__ bl,
                        __half* __restrict__ xl2){
    __shared__ float WS[HID*256];
    for (int i = threadIdx.x; i < HID*256; i += 256) WS[i] = Wl[i];
    __syncthreads();
    int lane = threadIdx.x & 63, wv = threadIdx.x >> 6;
    float4 b4 = *(const float4*)&bl[4*lane];
    int node0 = blockIdx.x * 32 + wv * 8;
    int nend = min(node0 + 8, NN);
    for (int n = node0; n < nend; ++n){
        const float* hr = h + n*HID;
        float4 a = {0.f,0.f,0.f,0.f};
        #pragma unroll 8
        for (int k = 0; k < HID; ++k){
            float hk = hr[k];
            float4 w = *(const float4*)&WS[k*256 + 4*lane];
            a.x += hk*w.x; a.y += hk*w.y; a.z += hk*w.z; a.w += hk*w.w;
        }
        ushort4 u;
        u.x = __half_as_ushort(__float2half_rn(a.x + b4.x));
        u.y = __half_as_ushort(__float2half_rn(a.y + b4.y));
        u.z = __half_as_ushort(__float2half_rn(a.z + b4.z));
        u.w = __half_as_ushort(__float2half_rn(a.w + b4.w));
        *(ushort4*)&xl2[(size_t)n*256 + 4*lane] = u;
    }
}

// ---- layer 2 edge aggregation + mish + pool (wave per dst node; lane = 4 cols) ----
// R3 structure; gathers are nontemporal (bypass L1) to widen the miss path.
__global__ __launch_bounds__(256) void k_edge2(const __half* __restrict__ xl2,
                        const float* __restrict__ h,
                        const float* __restrict__ Wr, const float* __restrict__ br,
                        const float* __restrict__ att, const float* __restrict__ b2,
                        const int* __restrict__ rp, const int* __restrict__ col,
                        const int* __restrict__ batch,
                        float* __restrict__ pool, float* __restrict__ cnt){
    int node = (blockIdx.x*blockDim.x + threadIdx.x) >> 6;
    int lane = threadIdx.x & 63;
    if (node >= NN) return;

    int co = 4*lane;                 // channel offset
    // xr2 row on the fly: xr[co+j] = br2[co+j] + sum_k h[node][k]*Wr2[k][co+j]
    float4 xr4 = *(const float4*)&br[co];
    {
        const float* hr = h + node*HID;
        #pragma unroll 8
        for (int k = 0; k < HID; ++k){
            float hk = hr[k];
            float4 w = *(const float4*)&Wr[k*256 + co];
            xr4.x += hk*w.x; xr4.y += hk*w.y; xr4.z += hk*w.z; xr4.w += hk*w.w;
        }
    }
    float4 at4 = *(const float4*)&att[co];
    float s = 0.f;
    float4 acc = {0.f,0.f,0.f,0.f};
    int lo = rp[node], hi = rp[node+1];
    int deg  = hi - lo;              // >= 1
    int degc = min(deg, 64);
    int cols = col[lo + min(lane, deg-1)];   // stage first 64 edge srcs
    int nbt = (degc + 3) >> 2;               // batches covering first degc edges
    int nb3 = ((nbt + 2)/3)*3;               // padded to multiple of 3 (masked)

    unsigned long long A0,A1,A2,A3, B0,B1,B2,B3, C0,C1,C2,C3;

#define GLD(P0,P1,P2,P3, b_) do { \
        int i0_ = 4*(b_); \
        int s0_ = __shfl(cols, min(i0_  , degc-1)); \
        int s1_ = __shfl(cols, min(i0_+1, degc-1)); \
        int s2_ = __shfl(cols, min(i0_+2, degc-1)); \
        int s3_ = __shfl(cols, min(i0_+3, degc-1)); \
        P0 = __builtin_nontemporal_load((const unsigned long long*)(xl2 + s0_*256 + co)); \
        P1 = __builtin_nontemporal_load((const unsigned long long*)(xl2 + s1_*256 + co)); \
        P2 = __builtin_nontemporal_load((const unsigned long long*)(xl2 + s2_*256 + co)); \
        P3 = __builtin_nontemporal_load((const unsigned long long*)(xl2 + s3_*256 + co)); \
    } while(0)

#define PROC1(q, ei_) do { \
        float2 f01 = __half22float2(__builtin_bit_cast(__half2, (unsigned)((q) & 0xffffffffu))); \
        float2 f23 = __half22float2(__builtin_bit_cast(__half2, (unsigned)((q) >> 32))); \
        float v0 = lrelu(f01.x + xr4.x), v1 = lrelu(f01.y + xr4.y); \
        float v2 = lrelu(f23.x + xr4.z), v3 = lrelu(f23.y + xr4.w); \
        float p = v0*at4.x + v1*at4.y + v2*at4.z + v3*at4.w; \
        p += __shfl_xor(p, 1); p += __shfl_xor(p, 2); \
        p += __shfl_xor(p, 4); p += __shfl_xor(p, 8); \
        float w = ((ei_) < degc) ? __expf(p) : 0.f; \
        s += w; \
        acc.x += w*f01.x; acc.y += w*f01.y; acc.z += w*f23.x; acc.w += w*f23.y; \
    } while(0)

#define PROC4(P0,P1,P2,P3, b_) do { \
        PROC1(P0, 4*(b_)); PROC1(P1, 4*(b_)+1); \
        PROC1(P2, 4*(b_)+2); PROC1(P3, 4*(b_)+3); } while(0)

    GLD(A0,A1,A2,A3, 0);
    GLD(B0,B1,B2,B3, 1);
    GLD(C0,C1,C2,C3, 2);
    for (int b = 3; b < nb3; b += 3){
        PROC4(A0,A1,A2,A3, b-3); GLD(A0,A1,A2,A3, b);
        PROC4(B0,B1,B2,B3, b-2); GLD(B0,B1,B2,B3, b+1);
        PROC4(C0,C1,C2,C3, b-1); GLD(C0,C1,C2,C3, b+2);
    }
    PROC4(A0,A1,A2,A3, nb3-3);
    PROC4(B0,B1,B2,B3, nb3-2);
    PROC4(C0,C1,C2,C3, nb3-1);

    // rare: rows with degree > 64
    for (int e = lo + 64; e < hi; ++e){
        int src = col[e];
        unsigned long long q = __builtin_nontemporal_load(
            (const unsigned long long*)(xl2 + src*256 + co));
        PROC1(q, 0);
    }
#undef GLD
#undef PROC1
#undef PROC4

    float inv = 1.f / (s + 1e-16f);
    float4 t; t.x = acc.x*inv; t.y = acc.y*inv; t.z = acc.z*inv; t.w = acc.w*inv;
    // sum over 4 heads (lanes differing in bits 4,5 share channel)
    t.x += __shfl_xor(t.x, 16); t.y += __shfl_xor(t.y, 16);
    t.z += __shfl_xor(t.z, 16); t.w += __shfl_xor(t.w, 16);
    t.x += __shfl_xor(t.x, 32); t.y += __shfl_xor(t.y, 32);
    t.z += __shfl_xor(t.z, 32); t.w += __shfl_xor(t.w, 32);
    if (lane < 16){
        int g = batch[node];
        float4 bb = *(const float4*)&b2[co];
        float o0 = 0.25f*t.x + bb.x;
        float o1 = 0.25f*t.y + bb.y;
        float o2 = 0.25f*t.z + bb.z;
        float o3 = 0.25f*t.w + bb.w;
        float* pg = pool + g*OUTC + co;
        atomicAdd(pg+0, mishf(o0));
        atomicAdd(pg+1, mishf(o1));
        atomicAdd(pg+2, mishf(o2));
        atomicAdd(pg+3, mishf(o3));
        if (lane == 0) atomicAdd(&cnt[g], 1.0f);
    }
}

__global__ void k_pool(const float* __restrict__ pool, const float* __restrict__ cnt,
                       float* __restrict__ out){
    int i = blockIdx.x*blockDim.x + threadIdx.x;
    if (i >= NG*OUTC) return;
    out[i] = pool[i] / fmaxf(cnt[i >> 6], 1.0f);
}

extern "C" void kernel_launch(void* const* d_in, const int* in_sizes, int n_in,
                              void* d_out, int out_size, void* d_ws, size_t ws_size,
                              hipStream_t stream){
    const float* x    = (const float*)d_in[0];
    const int*   ei   = (const int*)  d_in[1];
    const int*   batch= (const int*)  d_in[2];
    const float* Wl1  = (const float*)d_in[3];
    const float* bl1  = (const float*)d_in[4];
    const float* Wr1  = (const float*)d_in[5];
    const float* br1  = (const float*)d_in[6];
    const float* att1 = (const float*)d_in[7];
    const float* b1   = (const float*)d_in[8];
    const float* Wl2  = (const float*)d_in[9];
    const float* bl2  = (const float*)d_in[10];
    const float* Wr2  = (const float*)d_in[11];
    const float* br2  = (const float*)d_in[12];
    const float* att2 = (const float*)d_in[13];
    const float* b2   = (const float*)d_in[14];
    float* out = (float*)d_out;

    char* ws = (char*)d_ws;
    size_t off = 0;
    auto alloc = [&](size_t bytes)->char*{
        char* p = ws + off; off += (bytes + 255) & ~(size_t)255; return p;
    };
    __half* xl1  = (__half*)alloc((size_t)NN*HID*2);
    __half* xr1  = (__half*)alloc((size_t)NN*HID*2);
    float*  hbuf = (float*) alloc((size_t)NN*HID*4);
    __half* xl2  = (__half*)alloc((size_t)NN*256*2);
    int*    deg  = (int*)   alloc((size_t)NN*4);
    int*    rp   = (int*)   alloc((size_t)(NN+1)*4);
    int*    cur  = (int*)   alloc((size_t)NN*4);
    int*    col  = (int*)   alloc((size_t)ET*4);
    float*  pool = (float*) alloc((size_t)NG*OUTC*4);
    float*  cnt  = (float*) alloc((size_t)NG*4);
    int*    bsum = (int*)   alloc((size_t)512*4);

    const int NB = (NN + 255) / 256;   // 391

    hipMemsetAsync(deg,  0, (size_t)NN*4,      stream);
    hipMemsetAsync(pool, 0, (size_t)NG*OUTC*4, stream);
    hipMemsetAsync(cnt,  0, (size_t)NG*4,      stream);

    k_count <<<(ET+255)/256, 256, 0, stream>>>(ei, deg);
    k_scan_a<<<NB, 256, 0, stream>>>(deg, bsum);
    k_scan_b<<<1, 512, 0, stream>>>(bsum, NB);
    k_scan_c<<<NB, 256, 0, stream>>>(deg, bsum, rp, cur);
    k_fill  <<<(ET+255)/256, 256, 0, stream>>>(ei, cur, col);
    k_gemm1 <<<(NN+3)/4, 256, 0, stream>>>(x, Wl1, bl1, Wr1, br1, xl1, xr1);
    k_edge1 <<<(NN+3)/4, 256, 0, stream>>>(xl1, xr1, att1, b1, rp, col, hbuf);
    k_gemm2 <<<(NN+31)/32, 256, 0, stream>>>(hbuf, Wl2, bl2, xl2);
    k_edge2 <<<(NN+3)/4, 256, 0, stream>>>(xl2, hbuf, Wr2, br2, att2, b2, rp, col, batch, pool, cnt);
    k_pool  <<<(NG*OUTC+255)/256, 256, 0, stream>>>(pool, cnt, out);
}